// Round 15
// baseline (49.969 us; speedup 1.0000x reference)
//
#include <hip/hip_runtime.h>

// Implicit-GEMM MFMA v8 — waves=(p,mtile); A-frags in regs reused across dd;
// dd-max folded in-register; pool LDS + block reduce deleted; 1 barrier.
// Conv3d(3->16,k3,valid)+bias, /2, MaxPool3d(2), GlobalAvgPool, +bias, channel-sum.
// out[n] = (1/(2*14415)) * sum_{c,windows} max_window(conv_c) + sum_c(cb_c/2 + bias_c)
//
// Block = (ph, pdg, n), pd = 2*pdg + p. LDS xt[p][w][k], k=ci*16+drel*4+h
// (48 real), bf16, 16B-slot XOR swizzle (w&7). B[k][col] frags precomputed
// (col<16: hh=0 ch=col; col>=16: hh=1). kw via accumulating MFMAs on A rows
// shifted by kw. C: col=lane&31, row=(reg&3)+8*(reg>>2)+4*(lane>>5).
// Valid-window exclusions: pw=31 (mtile=1,half=1,jj=7), lanes l&16 (hh dup),
// p=1@pdg=7 (ragged) — all zeroed before the wave sum. Partials: 4/block.

using f32x16 = __attribute__((ext_vector_type(16))) float;
using bf16x8 = __attribute__((ext_vector_type(8))) short;
using s16x4  = __attribute__((ext_vector_type(4))) short;

__device__ inline unsigned short f2bf(float f) {
  unsigned int u = __float_as_uint(f);
  unsigned int r = 0x7fffu + ((u >> 16) & 1u);   // RNE for finite inputs
  return (unsigned short)((u + r) >> 16);
}

#define WS_FRAG_OFF 32768   // u32 units: frags at byte 128 KB (partials use 0..128 KB)

// ---- prep: B fragments for (dd, kchunk=ci, kw, lane). 1152 x 16B.
__global__ void prep_bfrags(const float* __restrict__ wgt, float* __restrict__ ws)
{
  int idx = blockIdx.x*256 + threadIdx.x;   // guard 1152
  if (idx >= 1152) return;
  short* fb = (short*)((unsigned int*)ws + WS_FRAG_OFF);
  int l = idx & 63, rest = idx >> 6;        // rest 0..17
  int kw = rest % 3, kc = (rest/3) % 3, dd = rest/9;
  int col = l & 31, half = l >> 5;
  int ch = col & 15, hh = col >> 4;
  short f[8];
  #pragma unroll
  for (int j = 0; j < 8; ++j) {
    int kloc = half*8 + j;                  // 0..15
    int drel = kloc >> 2, h = kloc & 3;
    int kd = drel - dd, kh = h - hh;
    bool ok = (kd >= 0) && (kd < 3) && (kh >= 0) && (kh < 3);
    float v = ok ? wgt[ch*81 + kc*27 + kd*9 + kh*3 + kw] : 0.f;
    f[j] = (short)f2bf(v);
  }
  bf16x8 q = { f[0], f[1], f[2], f[3], f[4], f[5], f[6], f[7] };
  *reinterpret_cast<bf16x8*>(&fb[idx*8]) = q;
}

__global__ __launch_bounds__(256, 2) void conv_mfma_kernel(
    const float* __restrict__ x, const float* __restrict__ ws_in,
    float* __restrict__ ws)
{
  __shared__ __align__(16) unsigned short xt[2][66*64];  // 16,896 B, swizzled

  const int tid = threadIdx.x;
  const int ph  = blockIdx.x;       // 0..30
  const int pdg = blockIdx.y;       // 0..7 -> pd = 2*pdg + p
  const int n   = blockIdx.z;       // 0..31
  const int l   = tid & 63;
  const int wid = tid >> 6;
  const int p = wid >> 1, mtile = wid & 1;
  const int half = l >> 5;
  const int w  = tid & 63;
  const int kq = tid >> 6;

  // ---- stage 6 unique d-slices: group g=(ci,s), s=0..5, abs d=4*pdg+s.
  // drel = s - 2p in [0,4): s<4 -> buf0, s>=2 -> buf1.
  const float* xn = x + (size_t)n*(3*32*64*64);
  const int D0 = 4*pdg, H0 = 2*ph;
  #pragma unroll
  for (int j = 0; j < 5; ++j) {
    int g = kq + 4*j;                 // wave-uniform
    if (g >= 18) break;
    int ci = g / 6, s = g - 6*ci;
    int d  = D0 + s; d = (d < 32) ? d : 31;   // clamp (ragged pdg=7; zeroed below)
    const float* xp = xn + (size_t)(ci*32 + d)*4096 + H0*64 + w;
    short va[4];
    #pragma unroll
    for (int h = 0; h < 4; ++h) va[h] = (short)f2bf(xp[h*64]);
    s16x4 v = { va[0], va[1], va[2], va[3] };
    if (s < 4) {
      int off = (ci*16 + s*4) ^ ((w & 7) << 3);
      *reinterpret_cast<s16x4*>(&xt[0][w*64 + off]) = v;
    }
    if (s >= 2) {
      int off = (ci*16 + (s - 2)*4) ^ ((w & 7) << 3);
      *reinterpret_cast<s16x4*>(&xt[1][w*64 + off]) = v;
    }
  }
  __syncthreads();

  // ---- A-frags for this wave's (p, mtile): 9 ds_read_b128, reused for both dd
  const int rowbase = mtile*32 + (l & 31);
  bf16x8 af[3][3];
  #pragma unroll
  for (int kc = 0; kc < 3; ++kc) {
    #pragma unroll
    for (int kw = 0; kw < 3; ++kw) {
      int row = rowbase + kw;
      int off = ((kc*2 + half)*8) ^ ((row & 7) << 3);
      af[kc][kw] = *reinterpret_cast<const bf16x8*>(&xt[p][row*64 + off]);
    }
  }

  // ---- 2 dd: 9 MFMA each from precomputed B frags; fold max in-register
  const short* fb = (const short*)((const unsigned int*)ws_in + WS_FRAG_OFF);
  float pv[8];
  #pragma unroll
  for (int jj = 0; jj < 8; ++jj) pv[jj] = -3.4e38f;
  #pragma unroll
  for (int dd = 0; dd < 2; ++dd) {
    bf16x8 bfr[3][3];
    #pragma unroll
    for (int kc = 0; kc < 3; ++kc)
      #pragma unroll
      for (int kw = 0; kw < 3; ++kw)
        bfr[kc][kw] = *reinterpret_cast<const bf16x8*>(
            &fb[(((dd*3 + kc)*3 + kw)*64 + l)*8]);
    f32x16 acc = {0.f,0.f,0.f,0.f,0.f,0.f,0.f,0.f,0.f,0.f,0.f,0.f,0.f,0.f,0.f,0.f};
    #pragma unroll
    for (int kc = 0; kc < 3; ++kc)
      #pragma unroll
      for (int kw = 0; kw < 3; ++kw)
        acc = __builtin_amdgcn_mfma_f32_32x32x16_bf16(af[kc][kw], bfr[kc][kw],
                                                      acc, 0, 0, 0);
    #pragma unroll
    for (int jj = 0; jj < 8; ++jj)
      pv[jj] = fmaxf(pv[jj], fmaxf(acc[2*jj], acc[2*jj + 1]));
  }

  // ---- hh-max across lane groups (l ^ 16), exclusions, wave sum
  #pragma unroll
  for (int jj = 0; jj < 8; ++jj)
    pv[jj] = fmaxf(pv[jj], __shfl_xor(pv[jj], 16, 64));
  if (mtile && half) pv[7] = 0.f;          // pw == 31
  float S = 0.f;
  #pragma unroll
  for (int jj = 0; jj < 8; ++jj) S += pv[jj];
  if (l & 16) S = 0.f;                     // hh duplicate lanes
  if (pdg == 7 && p == 1) S = 0.f;         // ragged pd
  #pragma unroll
  for (int off = 32; off > 0; off >>= 1) S += __shfl_down(S, off, 64);
  if (l == 0)
    ws[n*1024 + (pdg*31 + ph)*4 + wid] = S;  // 992 slots/n, all written
}

// ---- finalize: one block per n, 64 lanes stride the 992 partials.
__global__ void finalize_kernel(const float* __restrict__ ws,
                                const float* __restrict__ cb,
                                const float* __restrict__ bias,
                                float* __restrict__ out)
{
  const int n = blockIdx.x, l = threadIdx.x;
  float t = 0.f;
  #pragma unroll
  for (int r = 0; r < 16; ++r) {
    int s = l + r*64;
    if (s < 992) t += ws[n*1024 + s];
  }
  #pragma unroll
  for (int off = 32; off > 0; off >>= 1) t += __shfl_down(t, off, 64);
  if (l == 0) {
    float C = 0.f;
    #pragma unroll
    for (int c = 0; c < 16; ++c) C += cb[c]*0.5f + bias[c];
    out[n] = t * (1.0f/(2.0f*14415.0f)) + C;
  }
}

extern "C" void kernel_launch(void* const* d_in, const int* in_sizes, int n_in,
                              void* d_out, int out_size, void* d_ws, size_t ws_size,
                              hipStream_t stream) {
  (void)in_sizes; (void)n_in; (void)out_size; (void)ws_size;
  const float* x    = (const float*)d_in[0];
  const float* wgt  = (const float*)d_in[1];
  const float* cb   = (const float*)d_in[2];
  const float* bias = (const float*)d_in[3];
  float* out = (float*)d_out;
  float* ws  = (float*)d_ws;     // partials 128 KB @0; frags 18.4 KB @128 KB

  prep_bfrags<<<5, 256, 0, stream>>>(wgt, ws);
  dim3 grid(31, 8, 32);          // (ph, pdg, n) = 7936 blocks
  conv_mfma_kernel<<<grid, 256, 0, stream>>>(x, ws, ws);
  finalize_kernel<<<32, 64, 0, stream>>>(ws, cb, bias, out);
}